// Round 7
// baseline (1091.495 us; speedup 1.0000x reference)
//
#include <hip/hip_runtime.h>
#include <math.h>

#define TSTEPS 12
#define BATCH  2048
#define IMG    512
#define HIDN   1024
#define NCLASS 51
#define SCALE_X 1.7320508075688772f      // sqrt(1 + 2*e^0) = sqrt(3)

typedef __attribute__((ext_vector_type(8)))  _Float16 f16x8;
typedef __attribute__((ext_vector_type(2)))  _Float16 f16x2;
typedef __attribute__((ext_vector_type(16))) float    f32x16;

__device__ __forceinline__ float sigf(float x) {
    return 1.f / (1.f + __expf(-x));
}

// ---------------------------------------------------------------------------
// Fused fp16 MFMA GEMM + SRU recurrence, 32x32x16 MFMA path.
//   A fp16 row-major M x K, rows ordered (batch, t), t inner.
//   Bt: interleaved weight plane, row n = h*NCOMP + comp, length K.
//   Block tile: BM=192 rows (16 whole batches) x BN=64*TJ cols.
//   4 waves in 2x2; wave tile 96 x BN/2 = (3 x TJ) tiles of 32x32,
//   K-loop BK=32 (2 k-steps of 16), double-buffered global_load_lds.
//   Epilogue: two passes of 96 rows (8 whole batches): waves of that row-half
//   dump acc -> LDS fp16 U-tile (unioned with staging), block runs the
//   12-step SRU recurrence; writes h fp16 (hout) and/or mean_t h (hbar).
//   resid: NCOMP==4 -> comp 3 of U; NCOMP==3 -> global fp16 [M x HIDN].
// ---------------------------------------------------------------------------
template<int TJ, int NCOMP>
__global__ __launch_bounds__(256)
void gemm_sru(const _Float16* __restrict__ A, const _Float16* __restrict__ Bt,
              const _Float16* __restrict__ resid,
              const float* __restrict__ vc, const float* __restrict__ bias,
              _Float16* __restrict__ hout, float* __restrict__ hbar, int K) {
    constexpr int BM = 192, BN = 64 * TJ, HBN = BN / 2;
    constexpr int NCH = BN / NCOMP;               // channels per block
    constexpr int S_A = 2 * BM * 32;              // A staging halfs (2 bufs)
    constexpr int S_B = 2 * BN * 32;              // B staging halfs (2 bufs)
    constexpr int EPAD = BN + 8;
    constexpr int EPI = 96 * EPAD;                // one epilogue pass (96 rows)
    constexpr int TOT = (S_A + S_B) > EPI ? (S_A + S_B) : EPI;
    __shared__ __align__(16) _Float16 smem[TOT];

    const int tid  = threadIdx.x;
    const int lane = tid & 63;
    const int w    = tid >> 6;                    // wave 0..3
    const int bm   = blockIdx.y * BM;             // row origin (16 batches)
    const int bn   = blockIdx.x * BN;             // plane-row origin

    // ---- staging assignment (wave-uniform) ---------------------------------
    const bool isA  = (w < 2);
    const _Float16* splane = isA ? A : Bt;
    const int srow0 = isA ? (bm + (w & 1) * 96) : (bn + (w & 1) * HBN);
    const int nrows = isA ? 96 : HBN;             // rows staged by this wave
    const int lrow  = lane >> 2;                  // 16 rows per instruction
    const int lcol  = (lane & 3) * 8;             // halfs; 16 B per lane

    const int wy = (w >> 1) * 96;                 // wave compute origin
    const int wx = (w & 1) * HBN;

    f32x16 acc[3][TJ];
    #pragma unroll
    for (int i = 0; i < 3; ++i)
        #pragma unroll
        for (int j = 0; j < TJ; ++j)
            #pragma unroll
            for (int r = 0; r < 16; ++r) acc[i][j][r] = 0.f;

    const int l5  = lane >> 5;                    // 0/1: k-half selector
    const int m32 = lane & 31;                    // row/col within 32-tile

    const _Float16* gbase = splane + (size_t)(srow0 + lrow) * K + lcol;

    auto stage = [&](int buf, int k0) {
        const _Float16* g = gbase + k0;
        _Float16* l = isA ? (smem + buf * BM * 32 + (w & 1) * (96 * 32))
                          : (smem + S_A + buf * BN * 32 + (w & 1) * (HBN * 32));
        for (int j = 0; j < nrows / 16; ++j)
            __builtin_amdgcn_global_load_lds(
                (const __attribute__((address_space(1))) unsigned int*)(g + (size_t)j * 16 * K),
                (__attribute__((address_space(3))) unsigned int*)(l + j * 512),
                16, 0, 0);
    };

    stage(0, 0);                                  // prologue prefetch

    int cur = 0;
    for (int k0 = 0; k0 < K; k0 += 32) {
        __syncthreads();                          // drains prev-iter prefetch
        if (k0 + 32 < K) stage(cur ^ 1, k0 + 32);

        const _Float16* la = smem + cur * BM * 32;
        const _Float16* lb = smem + S_A + cur * BN * 32;
        #pragma unroll
        for (int ks = 0; ks < 2; ++ks) {          // two K=16 steps
            const int ko = ks * 16 + l5 * 8;
            f16x8 a[3], b[TJ];
            #pragma unroll
            for (int i = 0; i < 3; ++i)
                a[i] = *(const f16x8*)&la[(wy + i * 32 + m32) * 32 + ko];
            #pragma unroll
            for (int j = 0; j < TJ; ++j)
                b[j] = *(const f16x8*)&lb[(wx + j * 32 + m32) * 32 + ko];
            #pragma unroll
            for (int i = 0; i < 3; ++i)
                #pragma unroll
                for (int j = 0; j < TJ; ++j)
                    acc[i][j] = __builtin_amdgcn_mfma_f32_32x32x16_f16(
                        a[i], b[j], acc[i][j], 0, 0, 0);
        }
        cur ^= 1;
    }

    // ---- epilogue: two passes of 96 rows (8 whole batches each) ------------
    _Float16 (*uld)[EPAD] = (_Float16 (*)[EPAD])smem;
    const int bl  = tid >> 5;                     // local batch in pass 0..7
    const int pr  = tid & 31;                     // channel pair 0..31 (NCH=64)
                                                  // (NCH=32: pr&15 used)
    #pragma unroll
    for (int pass = 0; pass < 2; ++pass) {
        __syncthreads();                          // LDS free / prev pass done
        if ((w >> 1) == pass) {                   // dump this row-half's acc
            #pragma unroll
            for (int i = 0; i < 3; ++i)
                #pragma unroll
                for (int j = 0; j < TJ; ++j)
                    #pragma unroll
                    for (int r = 0; r < 16; ++r) {
                        const int row = i * 32 + (r & 3) + 8 * (r >> 2) + 4 * l5;
                        uld[row][wx + j * 32 + m32] = (_Float16)acc[i][j][r];
                    }
        }
        __syncthreads();

        // recurrence: 8 batches x (NCH/2) channel-pairs
        const int prm = pr & (NCH / 2 - 1);
        const int rep = (NCH == 64) ? 1 : 2;      // NCH=32: threads cover 2 b
        for (int q = 0; q < rep; ++q) {
            const int blq  = bl + q * 8;          // 0..7 (rep=1) or 0..15? no:
            // rep==2 -> 256 threads = 16 batch-slots x 16 pairs; map:
            const int blx  = (rep == 1) ? bl : (tid >> 4);
            if (rep == 2 && q == 1) break;        // single iteration, blx covers
            const int bloc = (rep == 1) ? blq : (blx & 7);
            const int extra= (rep == 1) ? 0 : (blx >> 3);   // unused (8 batches)
            (void)extra; (void)bloc;
            const int b8   = (rep == 1) ? bl : (blx & 7);
            if (rep == 2 && (blx >> 3) != 0 && false) {}
            const int bln  = b8;
            const int ch0  = ((rep == 1) ? pr : (tid & 15) * 1) * 2;
            const int ch   = (rep == 1) ? ch0 : (prm * 2);
            (void)ch0;
            const int gcol = blockIdx.x * NCH + ((rep == 1) ? pr * 2 : prm * 2);
            const int gb   = bm / 12 + pass * 8 + bln;

            const float2 vf  = *(const float2*)&vc[gcol];
            const float2 vr  = *(const float2*)&vc[HIDN + gcol];
            const float2 bfv = *(const float2*)&bias[gcol];
            const float2 brv = *(const float2*)&bias[HIDN + gcol];

            float c0 = 0.f, c1 = 0.f, s0 = 0.f, s1 = 0.f;
            const int chp = (rep == 1) ? pr * 2 : prm * 2;
            #pragma unroll
            for (int t = 0; t < TSTEPS; ++t) {
                const int row = bln * 12 + t;
                const float u0a = (float)uld[row][(chp    ) * NCOMP + 0];
                const float u1a = (float)uld[row][(chp    ) * NCOMP + 1];
                const float u2a = (float)uld[row][(chp    ) * NCOMP + 2];
                const float u0b = (float)uld[row][(chp + 1) * NCOMP + 0];
                const float u1b = (float)uld[row][(chp + 1) * NCOMP + 1];
                const float u2b = (float)uld[row][(chp + 1) * NCOMP + 2];
                float xta, xtb;
                if (NCOMP == 4) {
                    xta = (float)uld[row][(chp    ) * 4 + 3];
                    xtb = (float)uld[row][(chp + 1) * 4 + 3];
                } else {
                    const f16x2 xv = *(const f16x2*)
                        &resid[(size_t)(bm + pass * 96 + row) * HIDN + gcol];
                    xta = (float)xv[0]; xtb = (float)xv[1];
                }

                const float f0 = sigf(u1a + vf.x * c0 + bfv.x);
                c0 = f0 * c0 + (1.f - f0) * u0a;
                const float r0_ = sigf(u2a + vr.x * c0 + brv.x);
                const float th0 = 2.f * sigf(2.f * c0) - 1.f;
                const float hv0 = r0_ * th0 + (1.f - r0_) * xta * SCALE_X;

                const float f1 = sigf(u1b + vf.y * c1 + bfv.y);
                c1 = f1 * c1 + (1.f - f1) * u0b;
                const float r1_ = sigf(u2b + vr.y * c1 + brv.y);
                const float th1 = 2.f * sigf(2.f * c1) - 1.f;
                const float hv1 = r1_ * th1 + (1.f - r1_) * xtb * SCALE_X;

                if (hout && (rep == 1 || bl < 8)) {
                    f16x2 hv = { (_Float16)hv0, (_Float16)hv1 };
                    *(f16x2*)&hout[(size_t)(bm + pass * 96 + row) * HIDN + gcol] = hv;
                }
                s0 += hv0; s1 += hv1;
            }
            if (hbar && (rep == 1 || bl < 8)) {
                float2 hb = make_float2(s0 * (1.f / TSTEPS), s1 * (1.f / TSTEPS));
                *(float2*)&hbar[(size_t)gb * HIDN + gcol] = hb;
            }
        }
    }
}

// NOTE on rep-path above: for NCH=32 (layer0) only threads with bl<8
// (tid<256 always true for bl 0..7 -> tid>>5<8) — bl ranges 0..7 anyway,
// and prm folds pr into 0..15, so lanes pr>=16 duplicate pr-16's work and
// writes (same address, same value) — benign but wasteful; they are masked
// by (rep==1 || bl<8) for stores only when duplicated. Simpler and correct.

// ---------------------------------------------------------------------------
// Weight transpose + fp16 + channel-interleave:
//   W (K x N fp32), N = NCOMP*1024, col n = comp*1024 + h
//   -> plane row (h*NCOMP + comp), length K, fp16.
// ---------------------------------------------------------------------------
__global__ __launch_bounds__(256)
void wsplit_t(const float* __restrict__ W, _Float16* __restrict__ Wt,
              int K, int N, int ncomp) {
    __shared__ float tile[32][33];
    const int bn = blockIdx.x * 32;
    const int bk = blockIdx.y * 32;
    const int tx = threadIdx.x & 31;
    const int ty = threadIdx.x >> 5;              // 0..7
    #pragma unroll
    for (int i = 0; i < 32; i += 8)
        tile[ty + i][tx] = W[(size_t)(bk + ty + i) * N + bn + tx];
    __syncthreads();
    #pragma unroll
    for (int i = 0; i < 32; i += 8) {
        const int n = bn + ty + i;
        const int nr = (n & 1023) * ncomp + (n >> 10);   // h*ncomp + comp
        Wt[(size_t)nr * K + bk + tx] = (_Float16)tile[tx][ty + i];
    }
}

// elementwise fp32 -> fp16 convert (for x chunks)
__global__ __launch_bounds__(256)
void esplit(const float* __restrict__ src, _Float16* __restrict__ dst, int n) {
    int i = blockIdx.x * 256 + threadIdx.x;
    if (i < n) dst[i] = (_Float16)src[i];
}

// ---------------------------------------------------------------------------
// Final FC on time-averaged h: out[b,c] = hbar[b,:] . fc_w[:,c] + fc_b[c]
// ---------------------------------------------------------------------------
__global__ __launch_bounds__(64)
void final_fc(const float* __restrict__ hbar, const float* __restrict__ fcw,
              const float* __restrict__ fcb, float* __restrict__ out) {
    __shared__ float hrow[HIDN];
    const int b = blockIdx.x;
    for (int i = threadIdx.x; i < HIDN; i += 64)
        hrow[i] = hbar[(size_t)b * HIDN + i];
    __syncthreads();

    const int c = threadIdx.x;
    if (c < NCLASS) {
        float acc = fcb[c];
        #pragma unroll 8
        for (int k = 0; k < HIDN; ++k)
            acc = fmaf(hrow[k], fcw[(size_t)k * NCLASS + c], acc);
        out[(size_t)b * NCLASS + c] = acc;
    }
}

// ---------------------------------------------------------------------------
extern "C" void kernel_launch(void* const* d_in, const int* in_sizes, int n_in,
                              void* d_out, int out_size, void* d_ws, size_t ws_size,
                              hipStream_t stream) {
    const float* x   = (const float*)d_in[0];   // (B, T, IMG)
    const float* W0  = (const float*)d_in[1];   // (IMG, 4H)
    const float* W1  = (const float*)d_in[2];   // (H, 3H)
    const float* W2  = (const float*)d_in[3];   // (H, 3H)
    const float* vc0 = (const float*)d_in[4];
    const float* vc1 = (const float*)d_in[5];
    const float* vc2 = (const float*)d_in[6];
    const float* b0  = (const float*)d_in[7];
    const float* b1  = (const float*)d_in[8];
    const float* b2  = (const float*)d_in[9];
    const float* fcw = (const float*)d_in[10];  // (H, NCLASS)
    const float* fcb = (const float*)d_in[11];
    float* out = (float*)d_out;                 // (B, NCLASS)

    // ---- workspace carve-up -------------------------------------------------
    char* ws = (char*)d_ws;
    size_t off = 0;
    auto carve = [&](size_t bytes) { char* p = ws + off; off = (off + bytes + 255) & ~255ull; return p; };

    _Float16* W0t = (_Float16*)carve((size_t)4096 * 512 * 2);   // 4 MB
    _Float16* W1t = (_Float16*)carve((size_t)3072 * 1024 * 2);  // 6 MB
    _Float16* W2t = (_Float16*)carve((size_t)3072 * 1024 * 2);  // 6 MB
    const size_t W_BYTES = off;

    // per-batch arena: x16(12*512*2) + hA16(12*1024*2) + hB16 + hbar(1024*4)
    const size_t PER_B = 12ull * 512 * 2 + 2ull * 12 * 1024 * 2 + 1024ull * 4 + 1024;
    int CB = 32;
    if      (W_BYTES + 2048ull * PER_B <= ws_size) CB = 2048;
    else if (W_BYTES + 1024ull * PER_B <= ws_size) CB = 1024;
    else if (W_BYTES +  512ull * PER_B <= ws_size) CB = 512;
    else if (W_BYTES +  256ull * PER_B <= ws_size) CB = 256;
    else if (W_BYTES +  128ull * PER_B <= ws_size) CB = 128;
    else if (W_BYTES +   64ull * PER_B <= ws_size) CB = 64;
    const int MC = CB * TSTEPS;                  // rows; CB%16==0 -> 192 | MC

    _Float16* x16  = (_Float16*)carve((size_t)MC * 512 * 2);
    _Float16* hA16 = (_Float16*)carve((size_t)MC * 1024 * 2);
    _Float16* hB16 = (_Float16*)carve((size_t)MC * 1024 * 2);
    float*    hbar = (float*)carve((size_t)CB * 1024 * 4);

    const dim3 blk256(256);

    // ---- per-call weight prep (interleaved fp16 planes) --------------------
    wsplit_t<<<dim3(4096 / 32, 512 / 32),  blk256, 0, stream>>>(W0, W0t, 512, 4096, 4);
    wsplit_t<<<dim3(3072 / 32, 1024 / 32), blk256, 0, stream>>>(W1, W1t, 1024, 3072, 3);
    wsplit_t<<<dim3(3072 / 32, 1024 / 32), blk256, 0, stream>>>(W2, W2t, 1024, 3072, 3);

    for (int cb = 0; cb < BATCH / CB; ++cb) {
        const float* xc   = x   + (size_t)cb * CB * TSTEPS * IMG;
        float*       outc = out + (size_t)cb * CB * NCLASS;

        // layer 0: x->fp16; fused GEMM(K=512, BN=128, NCOMP=4) -> hA16
        esplit<<<dim3((MC * 512) / 256), blk256, 0, stream>>>(xc, x16, MC * 512);
        gemm_sru<2, 4><<<dim3(4096 / 128, MC / 192), blk256, 0, stream>>>(
            x16, W0t, nullptr, vc0, b0, hA16, nullptr, 512);

        // layer 1: fused GEMM(K=1024, BN=192, NCOMP=3) -> hB16
        gemm_sru<3, 3><<<dim3(3072 / 192, MC / 192), blk256, 0, stream>>>(
            hA16, W1t, hA16, vc1, b1, hB16, nullptr, 1024);

        // layer 2: fused; emit hbar only
        gemm_sru<3, 3><<<dim3(3072 / 192, MC / 192), blk256, 0, stream>>>(
            hB16, W2t, hB16, vc2, b2, nullptr, hbar, 1024);

        // final FC on time-averaged h
        final_fc<<<dim3(CB), dim3(64), 0, stream>>>(hbar, fcw, fcb, outc);
    }
}

// Round 8
// 764.440 us; speedup vs baseline: 1.4278x; 1.4278x over previous
//
#include <hip/hip_runtime.h>
#include <math.h>

#define TSTEPS 12
#define BATCH  2048
#define IMG    512
#define HIDN   1024
#define NCLASS 51
#define SCALE_X 1.7320508075688772f      // sqrt(1 + 2*e^0) = sqrt(3)

typedef __attribute__((ext_vector_type(8)))  _Float16 f16x8;
typedef __attribute__((ext_vector_type(2)))  _Float16 f16x2;
typedef __attribute__((ext_vector_type(16))) float    f32x16;

__device__ __forceinline__ float sigf(float x) {
    return 1.f / (1.f + __expf(-x));
}

// ===========================================================================
// Fragment-ordered ("chunked") layout, everywhere:
//   a matrix [R rows x K cols] fp16 is stored as 1KB chunks over
//   (rt = row/32, kt = k/16); chunk index = rt*(K/16) + kt; inside a chunk
//   lane l (0..63) owns halfs [l*8, l*8+8) = element (row = rt*32 + (l&31),
//   k = kt*16 + (l>>5)*8 + j).  This is exactly the v_mfma_f32_32x32x16_f16
//   A/B fragment (verified on-device R7), so LDS fragment reads are
//   ds_read_b128 at lane-stride 16B (conflict-free) and global_load_lds
//   stages whole chunks (uniform base + lane*16).
// ===========================================================================

// ---------------------------------------------------------------------------
// Fused fp16 MFMA GEMM + SRU recurrence. 32x32x16 MFMA.
//   A: fragment-ordered M x K (rows = (batch,t), t inner). Bt: fragment-
//   ordered weight plane (1024*NCOMP) x K, plane row = h*NCOMP + comp.
//   Block: BM=192 (16 batches) x BN=64*TJ. 4 waves 2x2, wave tile 96 x 32*TJ.
//   Epilogue: 2 passes of 96 rows: acc -> LDS U-tile -> 12-step recurrence;
//   h written fragment-ordered via LDS re-stage + coalesced 1KB chunk stores.
// ---------------------------------------------------------------------------
template<int TJ, int NCOMP>
__global__ __launch_bounds__(256, 2)
void gemm_sru(const _Float16* __restrict__ A, const _Float16* __restrict__ Bt,
              const _Float16* __restrict__ resid,
              const float* __restrict__ vc, const float* __restrict__ bias,
              _Float16* __restrict__ hout, float* __restrict__ hbar, int K) {
    constexpr int BN    = 64 * TJ;
    constexpr int NCH   = BN / NCOMP;          // channels per block
    constexpr int ATILE = 192 * 32;            // halfs (6144 = 12 KB)
    constexpr int BTILE = BN * 32;
    constexpr int S_A   = 2 * ATILE;
    constexpr int S_B   = 2 * BTILE;
    constexpr int EPAD  = BN + 8;
    constexpr int EPI   = 96 * EPAD;           // U-tile for one pass
    constexpr int HREG  = 96 * NCH;            // h staging for one pass
    constexpr int KTH   = NCH / 16;            // h k-tiles per rt in block
    constexpr int PAIRS = NCH / 2;
    constexpr int TOT   = (S_A + S_B) > (EPI + HREG) ? (S_A + S_B) : (EPI + HREG);
    __shared__ __align__(16) _Float16 smem[TOT];

    const int tid  = threadIdx.x;
    const int lane = tid & 63;
    const int w    = tid >> 6;                 // wave 0..3
    const int bm   = blockIdx.y * 192;
    const int bn   = blockIdx.x * BN;
    const int KT   = K >> 4;                   // k-tiles (16) per row-tile

    // ---- staging (wave-uniform): w<2 stage A halves, w>=2 stage B halves ---
    const bool isA = (w < 2);
    const int  nst = isA ? 3 : TJ;             // 32-row chunks this wave stages
    const _Float16* gsrc = isA ? A : Bt;
    const int rt0g = (isA ? (bm >> 5) : (bn >> 5)) + (w & 1) * nst;
    const _Float16* gbase = gsrc + (size_t)rt0g * KT * 512 + (lane << 3);
    const int lds0  = isA ? 0 : S_A;
    const int ltile = isA ? ATILE : BTILE;
    const int lhalf = (w & 1) * nst * 1024;    // local half-offset (halfs)

    auto stage = [&](int buf, int k0) {
        const _Float16* g = gbase + (size_t)(k0 >> 4) * 512;
        _Float16* l = smem + lds0 + buf * ltile + lhalf;
        for (int i = 0; i < nst; ++i)
            #pragma unroll
            for (int kt = 0; kt < 2; ++kt)
                __builtin_amdgcn_global_load_lds(
                    (const __attribute__((address_space(1))) unsigned int*)(g + ((size_t)i * KT + kt) * 512),
                    (__attribute__((address_space(3))) unsigned int*)(l + (i * 2 + kt) * 512),
                    16, 0, 0);
    };

    const int wy32 = (w >> 1) * 3;             // wave row-chunk origin
    const int wx32 = (w & 1) * TJ;             // wave col-chunk origin
    const int l5   = lane >> 5;
    const int m32  = lane & 31;

    f32x16 acc[3][TJ];
    #pragma unroll
    for (int i = 0; i < 3; ++i)
        #pragma unroll
        for (int j = 0; j < TJ; ++j)
            #pragma unroll
            for (int r = 0; r < 16; ++r) acc[i][j][r] = 0.f;

    stage(0, 0);
    int cur = 0;
    for (int k0 = 0; k0 < K; k0 += 32) {
        __syncthreads();                       // drains prev-iter prefetch
        if (k0 + 32 < K) stage(cur ^ 1, k0 + 32);

        const _Float16* la = smem + cur * ATILE;
        const _Float16* lb = smem + S_A + cur * BTILE;
        #pragma unroll
        for (int ks = 0; ks < 2; ++ks) {
            f16x8 a[3], b[TJ];
            #pragma unroll
            for (int i = 0; i < 3; ++i)
                a[i] = *(const f16x8*)&la[((wy32 + i) * 2 + ks) * 512 + (lane << 3)];
            #pragma unroll
            for (int j = 0; j < TJ; ++j)
                b[j] = *(const f16x8*)&lb[((wx32 + j) * 2 + ks) * 512 + (lane << 3)];
            #pragma unroll
            for (int i = 0; i < 3; ++i)
                #pragma unroll
                for (int j = 0; j < TJ; ++j)
                    acc[i][j] = __builtin_amdgcn_mfma_f32_32x32x16_f16(
                        a[i], b[j], acc[i][j], 0, 0, 0);
        }
        cur ^= 1;
    }

    // ---- epilogue: two passes of 96 rows (8 whole batches each) ------------
    _Float16 (*uld)[EPAD] = (_Float16 (*)[EPAD])smem;
    _Float16* hreg = smem + EPI;
    const int bl   = tid / PAIRS;              // local batch in pass
    const int pr   = tid % PAIRS;              // channel-pair index
    const int gcol = blockIdx.x * NCH + pr * 2;

    #pragma unroll
    for (int pass = 0; pass < 2; ++pass) {
        __syncthreads();                       // staging / prev pass done
        if ((w >> 1) == pass) {                // dump this row-half's acc
            #pragma unroll
            for (int i = 0; i < 3; ++i)
                #pragma unroll
                for (int j = 0; j < TJ; ++j)
                    #pragma unroll
                    for (int r = 0; r < 16; ++r) {
                        const int row = i * 32 + (r & 3) + 8 * (r >> 2) + 4 * l5;
                        uld[row][(wx32 + j) * 32 + m32] = (_Float16)acc[i][j][r];
                    }
        }
        __syncthreads();

        if (tid < 8 * PAIRS) {
            const float2 vf  = *(const float2*)&vc[gcol];
            const float2 vr  = *(const float2*)&vc[HIDN + gcol];
            const float2 bfv = *(const float2*)&bias[gcol];
            const float2 brv = *(const float2*)&bias[HIDN + gcol];
            const int ca = (pr * 2) * NCOMP, cb = (pr * 2 + 1) * NCOMP;

            float c0 = 0.f, c1 = 0.f, s0 = 0.f, s1 = 0.f;
            #pragma unroll
            for (int t = 0; t < TSTEPS; ++t) {
                const int row = bl * 12 + t;
                const float u0a = (float)uld[row][ca + 0];
                const float u1a = (float)uld[row][ca + 1];
                const float u2a = (float)uld[row][ca + 2];
                const float u0b = (float)uld[row][cb + 0];
                const float u1b = (float)uld[row][cb + 1];
                const float u2b = (float)uld[row][cb + 2];
                float xta, xtb;
                if (NCOMP == 4) {
                    xta = (float)uld[row][ca + 3];
                    xtb = (float)uld[row][cb + 3];
                } else {
                    const int grow = bm + pass * 96 + row;
                    const size_t gran = ((size_t)(grow >> 5) * KT + (gcol >> 4)) * 512
                                      + (size_t)((grow & 31) + ((gcol >> 3) & 1) * 32) * 8
                                      + (gcol & 7);
                    const f16x2 xv = *(const f16x2*)&resid[gran];
                    xta = (float)xv[0]; xtb = (float)xv[1];
                }

                const float f0 = sigf(u1a + vf.x * c0 + bfv.x);
                c0 = f0 * c0 + (1.f - f0) * u0a;
                const float r0_ = sigf(u2a + vr.x * c0 + brv.x);
                const float th0 = 2.f * sigf(2.f * c0) - 1.f;
                const float hv0 = r0_ * th0 + (1.f - r0_) * xta * SCALE_X;

                const float f1 = sigf(u1b + vf.y * c1 + bfv.y);
                c1 = f1 * c1 + (1.f - f1) * u0b;
                const float r1_ = sigf(u2b + vr.y * c1 + brv.y);
                const float th1 = 2.f * sigf(2.f * c1) - 1.f;
                const float hv1 = r1_ * th1 + (1.f - r1_) * xtb * SCALE_X;

                if (hout) {                    // stage h into LDS, frag layout
                    const int rtl  = row >> 5;
                    const int ktl  = pr >> 3;
                    const int lloc = (row & 31) + ((pr >> 2) & 1) * 32;
                    f16x2 hv = { (_Float16)hv0, (_Float16)hv1 };
                    *(f16x2*)&hreg[(rtl * KTH + ktl) * 512 + lloc * 8 + (pr & 3) * 2] = hv;
                }
                s0 += hv0; s1 += hv1;
            }
            if (hbar) {
                const int gb = bm / 12 + pass * 8 + bl;
                *(float2*)&hbar[(size_t)gb * HIDN + gcol] =
                    make_float2(s0 * (1.f / TSTEPS), s1 * (1.f / TSTEPS));
            }
        }

        if (hout) {                            // coalesced chunk copy to global
            __syncthreads();
            const int rtg0 = (bm + pass * 96) >> 5;
            for (int g = tid; g < HREG / 8; g += 256) {
                const int c = g >> 6, l = g & 63;
                const f16x8 v = *(const f16x8*)&hreg[c * 512 + l * 8];
                const int rtl = c / KTH, ktl = c % KTH;     // KTH is pow2
                const size_t gc = (size_t)(rtg0 + rtl) * 64 + blockIdx.x * KTH + ktl;
                *(f16x8*)&hout[gc * 512 + l * 8] = v;
            }
        }
    }
}

// ---------------------------------------------------------------------------
// Weight prep: W (K x N fp32, N = NC*1024, col n = comp*1024 + h) ->
// fragment-ordered fp16 plane, plane row n' = h*NC + comp, width K.
// One thread per output 16B granule (writes fully coalesced).
// ---------------------------------------------------------------------------
template<int NC>
__global__ __launch_bounds__(256)
void wsplit_t(const float* __restrict__ W, _Float16* __restrict__ Wt, int K) {
    const int N  = NC * 1024;
    const int KT = K >> 4;
    const int g  = blockIdx.x * 256 + threadIdx.x;
    const int c  = g >> 6, l = g & 63;
    const int rt = c / KT, kt = c - rt * KT;
    const int np = rt * 32 + (l & 31);         // plane row n'
    const int h  = np / NC, comp = np - h * NC;
    const int n  = comp * 1024 + h;
    const int k  = (kt << 4) + ((l >> 5) << 3);
    f16x8 v;
    #pragma unroll
    for (int j = 0; j < 8; ++j)
        v[j] = (_Float16)W[(size_t)(k + j) * N + n];
    *(f16x8*)&Wt[(size_t)g * 8] = v;
}

// ---------------------------------------------------------------------------
// x (rows x 512 fp32, row-major) -> fragment-ordered fp16 (K=512).
// ---------------------------------------------------------------------------
__global__ __launch_bounds__(256)
void esplit(const float* __restrict__ src, _Float16* __restrict__ dst) {
    const int g  = blockIdx.x * 256 + threadIdx.x;
    const int c  = g >> 6, l = g & 63;
    const int rt = c >> 5, kt = c & 31;        // KT = 512/16 = 32
    const int row = rt * 32 + (l & 31);
    const int k   = (kt << 4) + ((l >> 5) << 3);
    const float4 v0 = *(const float4*)&src[(size_t)row * 512 + k];
    const float4 v1 = *(const float4*)&src[(size_t)row * 512 + k + 4];
    f16x8 v = { (_Float16)v0.x, (_Float16)v0.y, (_Float16)v0.z, (_Float16)v0.w,
                (_Float16)v1.x, (_Float16)v1.y, (_Float16)v1.z, (_Float16)v1.w };
    *(f16x8*)&dst[(size_t)g * 8] = v;
}

// ---------------------------------------------------------------------------
// Final FC on time-averaged h: out[b,c] = hbar[b,:] . fc_w[:,c] + fc_b[c]
// ---------------------------------------------------------------------------
__global__ __launch_bounds__(64)
void final_fc(const float* __restrict__ hbar, const float* __restrict__ fcw,
              const float* __restrict__ fcb, float* __restrict__ out) {
    __shared__ float hrow[HIDN];
    const int b = blockIdx.x;
    for (int i = threadIdx.x; i < HIDN; i += 64)
        hrow[i] = hbar[(size_t)b * HIDN + i];
    __syncthreads();

    const int c = threadIdx.x;
    if (c < NCLASS) {
        float acc = fcb[c];
        #pragma unroll 8
        for (int k = 0; k < HIDN; ++k)
            acc = fmaf(hrow[k], fcw[(size_t)k * NCLASS + c], acc);
        out[(size_t)b * NCLASS + c] = acc;
    }
}

// ---------------------------------------------------------------------------
extern "C" void kernel_launch(void* const* d_in, const int* in_sizes, int n_in,
                              void* d_out, int out_size, void* d_ws, size_t ws_size,
                              hipStream_t stream) {
    const float* x   = (const float*)d_in[0];   // (B, T, IMG)
    const float* W0  = (const float*)d_in[1];   // (IMG, 4H)
    const float* W1  = (const float*)d_in[2];   // (H, 3H)
    const float* W2  = (const float*)d_in[3];   // (H, 3H)
    const float* vc0 = (const float*)d_in[4];
    const float* vc1 = (const float*)d_in[5];
    const float* vc2 = (const float*)d_in[6];
    const float* b0  = (const float*)d_in[7];
    const float* b1  = (const float*)d_in[8];
    const float* b2  = (const float*)d_in[9];
    const float* fcw = (const float*)d_in[10];  // (H, NCLASS)
    const float* fcb = (const float*)d_in[11];
    float* out = (float*)d_out;                 // (B, NCLASS)

    // ---- workspace carve-up -------------------------------------------------
    char* ws = (char*)d_ws;
    size_t off = 0;
    auto carve = [&](size_t bytes) { char* p = ws + off; off = (off + bytes + 255) & ~255ull; return p; };

    _Float16* W0t = (_Float16*)carve((size_t)4096 * 512 * 2);   // 4 MB
    _Float16* W1t = (_Float16*)carve((size_t)3072 * 1024 * 2);  // 6 MB
    _Float16* W2t = (_Float16*)carve((size_t)3072 * 1024 * 2);  // 6 MB
    const size_t W_BYTES = off;

    // per-batch arena: x16(12*512*2) + hA16(12*1024*2) + hB16 + hbar(1024*4)
    const size_t PER_B = 12ull * 512 * 2 + 2ull * 12 * 1024 * 2 + 1024ull * 4 + 1024;
    int CB = 32;
    if      (W_BYTES + 2048ull * PER_B <= ws_size) CB = 2048;
    else if (W_BYTES + 1024ull * PER_B <= ws_size) CB = 1024;
    else if (W_BYTES +  512ull * PER_B <= ws_size) CB = 512;
    else if (W_BYTES +  256ull * PER_B <= ws_size) CB = 256;
    else if (W_BYTES +  128ull * PER_B <= ws_size) CB = 128;
    else if (W_BYTES +   64ull * PER_B <= ws_size) CB = 64;
    const int MC = CB * TSTEPS;                  // rows; CB%16==0 -> 192 | MC

    _Float16* x16  = (_Float16*)carve((size_t)MC * 512 * 2);
    _Float16* hA16 = (_Float16*)carve((size_t)MC * 1024 * 2);
    _Float16* hB16 = (_Float16*)carve((size_t)MC * 1024 * 2);
    float*    hbar = (float*)carve((size_t)CB * 1024 * 4);

    const dim3 blk256(256);

    // ---- per-call weight prep (fragment-ordered fp16 planes) ---------------
    wsplit_t<4><<<dim3((4096 / 32) * (512 / 16) * 64 / 256),  blk256, 0, stream>>>(W0, W0t, 512);
    wsplit_t<3><<<dim3((3072 / 32) * (1024 / 16) * 64 / 256), blk256, 0, stream>>>(W1, W1t, 1024);
    wsplit_t<3><<<dim3((3072 / 32) * (1024 / 16) * 64 / 256), blk256, 0, stream>>>(W2, W2t, 1024);

    for (int cb = 0; cb < BATCH / CB; ++cb) {
        const float* xc   = x   + (size_t)cb * CB * TSTEPS * IMG;
        float*       outc = out + (size_t)cb * CB * NCLASS;

        // layer 0: x -> fragment fp16; fused GEMM(K=512, BN=128) -> hA16
        esplit<<<dim3(MC / 4), blk256, 0, stream>>>(xc, x16);
        gemm_sru<2, 4><<<dim3(4096 / 128, MC / 192), blk256, 0, stream>>>(
            x16, W0t, nullptr, vc0, b0, hA16, nullptr, 512);

        // layer 1: fused GEMM(K=1024, BN=192) -> hB16
        gemm_sru<3, 3><<<dim3(3072 / 192, MC / 192), blk256, 0, stream>>>(
            hA16, W1t, hA16, vc1, b1, hB16, nullptr, 1024);

        // layer 2: fused; emit hbar only
        gemm_sru<3, 3><<<dim3(3072 / 192, MC / 192), blk256, 0, stream>>>(
            hB16, W2t, hB16, vc2, b2, nullptr, hbar, 1024);

        // final FC on time-averaged h
        final_fc<<<dim3(CB), dim3(64), 0, stream>>>(hbar, fcw, fcb, outc);
    }
}